// Round 3
// baseline (260.793 us; speedup 1.0000x reference)
//
#include <hip/hip_runtime.h>
#include <cmath>

#define T_LEN   480000
#define BATCH   64
#define CHUNK   64                        /* samples per thread (contiguous run) */
#define WARM    16                        /* |pole|=0.414 -> 0.414^16 ~ 7.6e-7 */
#define TPB     256
#define SEG_PER_ROW (T_LEN / CHUNK)       /* 7500 */
#define BPR     ((SEG_PER_ROW + TPB - 1) / TPB)   /* 30 blocks per row */
#define NV      ((WARM + CHUNK) / 4)      /* 20 float4 loads per thread */
#define NW      (WARM / 4)                /* 4 warm-up float4 */

/* Pure streaming design (round-3 theory: the ~80us floor of all previous
   variants was average-MLP-bound: ~5KB/wave in flight during a ~10% duty
   cycle, with vmcnt drains at every LDS commit.  Here: NO LDS, NO barriers,
   no phases -- each thread issues 20 independent float4 loads (20KB/wave in
   flight), computes its private recurrence from registers, stores directly.
   Memory issue never stops chip-wide; waves drift freely. */

#define STEP(XN, YN)                                            \
    {                                                           \
        float u_ = fmaf(B0, (XN), fmaf(B1, x1, B2 * x2));       \
        (YN) = fmaf(-A1, y1, fmaf(-A2, y2, u_));                \
        x2 = x1; x1 = (XN); y2 = y1; y1 = (YN);                 \
    }

__global__ __launch_bounds__(TPB) void allpass_kernel(
    const float* __restrict__ x, float* __restrict__ y,
    float B0, float B1, float B2, float A1, float A2)
{
    const int row = blockIdx.x / BPR;
    const int seg = (blockIdx.x % BPR) * TPB + threadIdx.x;
    if (seg >= SEG_PER_ROW) return;       /* tail: 76/256 threads in last block */
    const size_t base = (size_t)row * T_LEN + (size_t)seg * CHUNK;

    /* ---- issue ALL loads first: 20 independent float4 in flight ---- */
    float4 v[NV];
    if (seg != 0) {
        const float* __restrict__ xp = x + base - WARM;   /* 64B-aligned */
        #pragma unroll
        for (int j = 0; j < NV; ++j)
            v[j] = *(const float4*)(xp + 4 * j);
    } else {
        /* zero state before t=0 (only thread seg==0 of each row) */
        #pragma unroll
        for (int j = 0; j < NW; ++j)
            v[j] = make_float4(0.f, 0.f, 0.f, 0.f);
        const float* __restrict__ xp = x + base;
        #pragma unroll
        for (int j = NW; j < NV; ++j)
            v[j] = *(const float4*)(xp + 4 * (j - NW));
    }

    /* ---- private recurrence: 16 warm-up + 64 real steps ---- */
    float x1 = 0.f, x2 = 0.f, y1 = 0.f, y2 = 0.f;
    #pragma unroll
    for (int j = 0; j < NW; ++j) {        /* warm-up, results discarded */
        float t;
        STEP(v[j].x, t); STEP(v[j].y, t); STEP(v[j].z, t); STEP(v[j].w, t);
    }
    float* __restrict__ yp = y + base;
    #pragma unroll
    for (int j = NW; j < NV; ++j) {
        float4 yv;
        STEP(v[j].x, yv.x); STEP(v[j].y, yv.y);
        STEP(v[j].z, yv.z); STEP(v[j].w, yv.w);
        /* per-thread contiguous 256B run; L2 merges lane-strided float4
           stores to full lines (verified: WRITE_SIZE ideal in rounds 1-2) */
        *(float4*)(yp + 4 * (j - NW)) = yv;
    }
}

extern "C" void kernel_launch(void* const* d_in, const int* in_sizes, int n_in,
                              void* d_out, int out_size, void* d_ws, size_t ws_size,
                              hipStream_t stream) {
    const float* x = (const float*)d_in[0];
    float* y = (float*)d_out;

    const double sample_rate = 16000.0, central_freq = 4000.0, Q = 0.707;
    const double w0 = 2.0 * M_PI * central_freq / sample_rate;
    const double alpha = sin(w0) / (2.0 * Q);
    const double cw = cos(w0);
    const double a0 = 1.0 + alpha;
    const float B0 = (float)((1.0 - alpha) / a0);
    const float B1 = (float)((-2.0 * cw) / a0);
    const float B2 = (float)((1.0 + alpha) / a0);
    const float A1 = (float)((-2.0 * cw) / a0);
    const float A2 = (float)((1.0 - alpha) / a0);

    const int blocks = BATCH * BPR;   /* 1920 */
    allpass_kernel<<<blocks, TPB, 0, stream>>>(x, y, B0, B1, B2, A1, A2);
}

// Round 5
// 206.268 us; speedup vs baseline: 1.2643x; 1.2643x over previous
//
#include <hip/hip_runtime.h>
#include <cmath>

#define T_LEN   480000
#define BATCH   64
#define CHUNK   16                       /* samples per thread */
#define WARM    16                       /* |pole|=0.414 -> 0.414^16 ~ 7.6e-7 */
#define TPB     256
#define TS      (TPB * CHUNK)            /* 4096 samples per tile */
#define TPR     ((T_LEN + TS - 1) / TS)  /* 118 tiles per row */
#define NLOAD_MAX (TS + WARM)            /* 4112 */
#define NITER   ((NLOAD_MAX + TPB * 4 - 1) / (TPB * 4))   /* 5 */
/* quad skew: +4 floats per 32 -> aligned float4 stays contiguous, all
   access patterns bank-uniform (8 lanes/quad). */
#define LDS_SLOTS (NLOAD_MAX + ((NLOAD_MAX >> 5) << 2))  /* 18.5 KB */

/* native vector type: __builtin_nontemporal_* rejects HIP_vector_type */
typedef float f32x4 __attribute__((ext_vector_type(4)));

__device__ __forceinline__ int slot4(int i) { return i + ((i >> 5) << 2); }

#define STEP(XN, YN)                                            \
    {                                                           \
        float u_ = fmaf(B0, (XN), fmaf(B1, x1, B2 * x2));       \
        (YN) = fmaf(-A1, y1, fmaf(-A2, y2, u_));                \
        x2 = x1; x1 = (XN); y2 = y1; y1 = (YN);                 \
    }

/* R4 theory: reads run at ~1 TB/s because both zero-reuse streams churn
   L2/LLC (every x fill + y allocate forces an eviction; the read stream
   pays the round trips).  Fix under test: nontemporal on BOTH streams.
   Stores stay lane-contiguous (full 64B lines per wave-instruction) via
   the LDS-staged epilogue so nt writes are posted, not RMW. */

__global__ __launch_bounds__(TPB) void allpass_kernel(
    const float* __restrict__ x, float* __restrict__ y,
    float B0, float B1, float B2, float A1, float A2)
{
    __shared__ __align__(16) float lds[LDS_SLOTS];
    const int tid  = threadIdx.x;
    const int row  = blockIdx.x / TPR;
    const int tb   = blockIdx.x % TPR;
    const int sbase = tb * TS;
    const int ns   = min(TS, T_LEN - sbase);      /* 4096, last tile 768 */
    const float* __restrict__ xr = x + (size_t)row * T_LEN + sbase;
    float* __restrict__ yr       = y + (size_t)row * T_LEN + sbase;
    const int nload = ns + WARM;

    /* ---- phase 1: all nt loads issued back-to-back (unrolled), then
       ds_writes.  Lane-contiguous: lane i reads bytes [16i,16i+16). ---- */
    f32x4 vbuf[NITER];
    #pragma unroll
    for (int j = 0; j < NITER; ++j) {
        const int i4 = tid * 4 + j * (TPB * 4);
        if (i4 < nload) {
            if (tb == 0 && i4 < WARM)
                vbuf[j] = (f32x4){0.f, 0.f, 0.f, 0.f};
            else
                vbuf[j] = __builtin_nontemporal_load(
                              (const f32x4*)(xr - WARM + i4));
        }
    }
    #pragma unroll
    for (int j = 0; j < NITER; ++j) {
        const int i4 = tid * 4 + j * (TPB * 4);
        if (i4 < nload)
            *(f32x4*)&lds[slot4(i4)] = vbuf[j];
    }
    __syncthreads();

    /* ---- phase 2: private recurrence, 16 warm-up + 16 real steps ---- */
    f32x4 yq[CHUNK / 4];
    const int ls = tid * CHUNK;
    const bool active = (ls < ns);
    if (active) {
        float x1 = 0.f, x2 = 0.f, y1 = 0.f, y2 = 0.f;
        #pragma unroll
        for (int t4 = 0; t4 < WARM; t4 += 4) {
            f32x4 xv = *(const f32x4*)&lds[slot4(ls + t4)];
            float t;
            STEP(xv.x, t); STEP(xv.y, t); STEP(xv.z, t); STEP(xv.w, t);
        }
        #pragma unroll
        for (int t4 = 0; t4 < CHUNK; t4 += 4) {
            f32x4 xv = *(const f32x4*)&lds[slot4(ls + WARM + t4)];
            f32x4 yv;
            STEP(xv.x, yv.x); STEP(xv.y, yv.y);
            STEP(xv.z, yv.z); STEP(xv.w, yv.w);
            yq[t4 / 4] = yv;
        }
    }
    __syncthreads();                              /* LDS x-reads done */

    /* ---- phase 3: stage y through LDS, then lane-contiguous nt stores ---- */
    if (active) {
        #pragma unroll
        for (int t4 = 0; t4 < CHUNK; t4 += 4)
            *(f32x4*)&lds[slot4(ls + t4)] = yq[t4 / 4];
    }
    __syncthreads();

    #pragma unroll
    for (int j = 0; j < NITER - 1; ++j) {         /* 4 iters cover TS */
        const int i4 = tid * 4 + j * (TPB * 4);
        if (i4 < ns) {
            f32x4 v = *(const f32x4*)&lds[slot4(i4)];
            __builtin_nontemporal_store(v, (f32x4*)(yr + i4));
        }
    }
}

extern "C" void kernel_launch(void* const* d_in, const int* in_sizes, int n_in,
                              void* d_out, int out_size, void* d_ws, size_t ws_size,
                              hipStream_t stream) {
    const float* x = (const float*)d_in[0];
    float* y = (float*)d_out;

    const double sample_rate = 16000.0, central_freq = 4000.0, Q = 0.707;
    const double w0 = 2.0 * M_PI * central_freq / sample_rate;
    const double alpha = sin(w0) / (2.0 * Q);
    const double cw = cos(w0);
    const double a0 = 1.0 + alpha;
    const float B0 = (float)((1.0 - alpha) / a0);
    const float B1 = (float)((-2.0 * cw) / a0);
    const float B2 = (float)((1.0 + alpha) / a0);
    const float A1 = (float)((-2.0 * cw) / a0);
    const float A2 = (float)((1.0 - alpha) / a0);

    const int blocks = BATCH * TPR;   /* 7552 */
    allpass_kernel<<<blocks, TPB, 0, stream>>>(x, y, B0, B1, B2, A1, A2);
}